// Round 1
// baseline (710.898 us; speedup 1.0000x reference)
//
#include <hip/hip_runtime.h>

constexpr int NB  = 32;   // basins
constexpr int D   = 64;   // core dim
constexpr int D4  = 16;   // D/4
constexpr int TOPC = 6;   // f32 candidates refined in f64

__global__ void util_init_kernel(const float* __restrict__ util_in,
                                 float* __restrict__ util_out) {
    int i = threadIdx.x;
    if (i < NB) util_out[i] = util_in[i];
}

__global__ __launch_bounds__(256) void geocore_kernel(
    const float* __restrict__ z,
    const float* __restrict__ protos,
    float* __restrict__ act_out,
    float* __restrict__ assign_out,
    float* __restrict__ util_out,
    int nrows)
{
    __shared__ int hist[NB];
    if (threadIdx.x < NB) hist[threadIdx.x] = 0;
    __syncthreads();

    const int row = blockIdx.x * blockDim.x + threadIdx.x;

    if (row < nrows) {
        const float4* __restrict__ z4 =
            reinterpret_cast<const float4*>(z) + (size_t)row * D4;
        float4 zr[D4];
#pragma unroll
        for (int k = 0; k < D4; ++k) zr[k] = z4[k];

        // ---- f32 sims: prototypes via uniform (scalar) loads ----
        float sims[NB];
#pragma unroll
        for (int n = 0; n < NB; ++n) {
            const float* __restrict__ p = protos + n * D;
            float acc = 0.0f;
#pragma unroll
            for (int k = 0; k < D4; ++k) {
                acc = fmaf(zr[k].x, p[4*k+0], acc);
                acc = fmaf(zr[k].y, p[4*k+1], acc);
                acc = fmaf(zr[k].z, p[4*k+2], acc);
                acc = fmaf(zr[k].w, p[4*k+3], acc);
            }
            sims[n] = acc;
        }

        // ---- f32 top-6 candidates (ties -> lowest index) ----
        unsigned sel = 0u;
        int cand[TOPC];
#pragma unroll
        for (int c = 0; c < TOPC; ++c) {
            float best = -3.0f;
            int bi = 0;
#pragma unroll
            for (int n = 0; n < NB; ++n) {
                bool take = (((sel >> n) & 1u) == 0u) && (sims[n] > best);
                best = take ? sims[n] : best;
                bi   = take ? n : bi;
            }
            sel |= (1u << bi);
            cand[c] = bi;
        }

        // ---- f64 refine of the 6 candidates (match f64 golden ordering) ----
        double cval[TOPC];
#pragma unroll
        for (int c = 0; c < TOPC; ++c) {
            const float4* __restrict__ pr =
                reinterpret_cast<const float4*>(protos) + cand[c] * D4;
            double acc = 0.0;
#pragma unroll
            for (int k = 0; k < D4; ++k) {
                float4 pv = pr[k];
                acc = fma((double)zr[k].x, (double)pv.x, acc);
                acc = fma((double)zr[k].y, (double)pv.y, acc);
                acc = fma((double)zr[k].z, (double)pv.z, acc);
                acc = fma((double)zr[k].w, (double)pv.w, acc);
            }
            cval[c] = acc;
        }

        // ---- top-3 of 6 by f64 value (ties -> lowest basin index) ----
        int ti[3]; double tv[3];
        unsigned sel6 = 0u;
#pragma unroll
        for (int r = 0; r < 3; ++r) {
            double best = -1.0e300;
            int bq = 0, bidx = 1000;
#pragma unroll
            for (int q = 0; q < TOPC; ++q) {
                bool free_ = (((sel6 >> q) & 1u) == 0u);
                bool take = free_ && ((cval[q] > best) ||
                                      (cval[q] == best && cand[q] < bidx));
                best = take ? cval[q] : best;
                bq   = take ? q : bq;
                bidx = take ? cand[q] : bidx;
            }
            sel6 |= (1u << bq);
            ti[r] = bidx;
            tv[r] = best;
        }

        const int i0 = ti[0], i1 = ti[1], i2 = ti[2];
        // softmax over the 3 kept values / temp 5.0 (others exp(-2e8) == 0)
        const float e1 = __expf((float)((tv[1] - tv[0]) * 0.2));
        const float e2 = __expf((float)((tv[2] - tv[0]) * 0.2));
        const float inv = 1.0f / (1.0f + e1 + e2);
        const float a0 = inv, a1 = e1 * inv, a2 = e2 * inv;

        // ---- write activations (32 floats, 3 nonzero) ----
        float4* __restrict__ o4 =
            reinterpret_cast<float4*>(act_out) + (size_t)row * (NB / 4);
#pragma unroll
        for (int j = 0; j < NB / 4; ++j) {
            float4 o;
            const int nb = 4 * j;
            o.x = (nb+0 == i0) ? a0 : (nb+0 == i1) ? a1 : (nb+0 == i2) ? a2 : 0.0f;
            o.y = (nb+1 == i0) ? a0 : (nb+1 == i1) ? a1 : (nb+1 == i2) ? a2 : 0.0f;
            o.z = (nb+2 == i0) ? a0 : (nb+2 == i1) ? a1 : (nb+2 == i2) ? a2 : 0.0f;
            o.w = (nb+3 == i0) ? a0 : (nb+3 == i1) ? a1 : (nb+3 == i2) ? a2 : 0.0f;
            o4[j] = o;
        }

        assign_out[row] = (float)i0;
        atomicAdd(&hist[i0], 1);
    }

    __syncthreads();
    if (threadIdx.x < NB) {
        // rotate bin order by block to spread same-address atomic contention
        const int b = (threadIdx.x + blockIdx.x) & (NB - 1);
        const int c = hist[b];
        if (c > 0) atomicAdd(&util_out[b], (float)c);
    }
}

extern "C" void kernel_launch(void* const* d_in, const int* in_sizes, int n_in,
                              void* d_out, int out_size, void* d_ws, size_t ws_size,
                              hipStream_t stream) {
    const float* z      = (const float*)d_in[0];
    const float* protos = (const float*)d_in[1];
    const float* util   = (const float*)d_in[2];
    const int nrows = in_sizes[0] / D;

    float* act_out    = (float*)d_out;
    float* assign_out = act_out + (size_t)nrows * NB;
    float* util_out   = assign_out + nrows;

    util_init_kernel<<<1, 64, 0, stream>>>(util, util_out);
    const int blocks = (nrows + 255) / 256;
    geocore_kernel<<<blocks, 256, 0, stream>>>(z, protos, act_out, assign_out,
                                               util_out, nrows);
}

// Round 2
// 559.645 us; speedup vs baseline: 1.2703x; 1.2703x over previous
//
#include <hip/hip_runtime.h>

constexpr int NB = 32;   // basins
constexpr int D  = 64;   // core dim
constexpr int D4 = 16;   // D/4

__global__ void util_init_kernel(const float* __restrict__ util_in,
                                 float* __restrict__ util_out) {
    if (threadIdx.x < NB) util_out[threadIdx.x] = util_in[threadIdx.x];
}

__global__ __launch_bounds__(256, 4) void geocore_kernel(
    const float* __restrict__ z,
    const float* __restrict__ protos,
    float* __restrict__ act_out,
    float* __restrict__ assign_out,
    float* __restrict__ util_out,
    int nrows)
{
    __shared__ int hist[NB];
    if (threadIdx.x < NB) hist[threadIdx.x] = 0;
    __syncthreads();

    const int row = blockIdx.x * blockDim.x + threadIdx.x;

    if (row < nrows) {
        const float4* __restrict__ z4 =
            reinterpret_cast<const float4*>(z) + (size_t)row * D4;

        // ---- f32 sims: stream z in 4 chunks of 16 floats; 32 accumulators ----
        float sims[NB];
#pragma unroll
        for (int n = 0; n < NB; ++n) sims[n] = 0.0f;

#pragma unroll
        for (int g = 0; g < 4; ++g) {
            float zc[16];
#pragma unroll
            for (int q = 0; q < 4; ++q) {
                float4 t = z4[4 * g + q];
                zc[4 * q + 0] = t.x; zc[4 * q + 1] = t.y;
                zc[4 * q + 2] = t.z; zc[4 * q + 3] = t.w;
            }
#pragma unroll
            for (int n = 0; n < NB; ++n) {
                const float* __restrict__ p = protos + n * D + g * 16;
                float a = sims[n];
#pragma unroll
                for (int j = 0; j < 16; ++j) a = fmaf(zc[j], p[j], a);
                sims[n] = a;
            }
        }

        // ---- f32 top-4 (ties -> lowest index via strict >) ----
        float tv[4]; int ti[4];
        unsigned sel = 0u;
#pragma unroll
        for (int r = 0; r < 4; ++r) {
            float best = -1.0e30f; int bi = 0;
#pragma unroll
            for (int n = 0; n < NB; ++n) {
                bool take = (((sel >> n) & 1u) == 0u) && (sims[n] > best);
                best = take ? sims[n] : best;
                bi   = take ? n : bi;
            }
            sel |= (1u << bi);
            tv[r] = best; ti[r] = bi;
        }

        int i0 = ti[0], i1 = ti[1], i2 = ti[2];
        float a0, a1, a2;

        // f32 dot error vs f64 golden is < ~4e-6; if every adjacent gap
        // among top-4 exceeds EPS, f32 ordering == f64 ordering.
        const float EPS = 1.0e-5f;
        const bool ambiguous = (tv[0] - tv[1] < EPS) ||
                               (tv[1] - tv[2] < EPS) ||
                               (tv[2] - tv[3] < EPS);

        if (!ambiguous) {
            // softmax over kept 3 / temp 5.0 (masked entries underflow to 0)
            const float e1 = __expf((tv[1] - tv[0]) * 0.2f);
            const float e2 = __expf((tv[2] - tv[0]) * 0.2f);
            const float inv = 1.0f / (1.0f + e1 + e2);
            a0 = inv; a1 = e1 * inv; a2 = e2 * inv;
        } else {
            // ---- rare slow path: extend to top-6, refine in f64 ----
            int cand[6];
            cand[0] = ti[0]; cand[1] = ti[1]; cand[2] = ti[2]; cand[3] = ti[3];
#pragma unroll
            for (int r = 4; r < 6; ++r) {
                float best = -1.0e30f; int bi = 0;
#pragma unroll
                for (int n = 0; n < NB; ++n) {
                    bool take = (((sel >> n) & 1u) == 0u) && (sims[n] > best);
                    best = take ? sims[n] : best;
                    bi   = take ? n : bi;
                }
                sel |= (1u << bi);
                cand[r] = bi;
            }

            double cv[6];
#pragma unroll
            for (int c = 0; c < 6; ++c) cv[c] = 0.0;
#pragma unroll
            for (int g = 0; g < 4; ++g) {
                float zc[16];
#pragma unroll
                for (int q = 0; q < 4; ++q) {
                    float4 t = z4[4 * g + q];
                    zc[4 * q + 0] = t.x; zc[4 * q + 1] = t.y;
                    zc[4 * q + 2] = t.z; zc[4 * q + 3] = t.w;
                }
#pragma unroll
                for (int c = 0; c < 6; ++c) {
                    const float* __restrict__ p = protos + cand[c] * D + g * 16;
                    double a = cv[c];
#pragma unroll
                    for (int j = 0; j < 16; ++j)
                        a = fma((double)zc[j], (double)p[j], a);
                    cv[c] = a;
                }
            }

            // top-3 of 6 by f64 value, ties -> lowest basin index
            int oi[3]; double ov[3];
            unsigned s6 = 0u;
#pragma unroll
            for (int r = 0; r < 3; ++r) {
                double best = -1.0e300; int bq = 0, bidx = 1000;
#pragma unroll
                for (int q = 0; q < 6; ++q) {
                    bool free_ = (((s6 >> q) & 1u) == 0u);
                    bool take = free_ && ((cv[q] > best) ||
                                          (cv[q] == best && cand[q] < bidx));
                    best = take ? cv[q] : best;
                    bq   = take ? q : bq;
                    bidx = take ? cand[q] : bidx;
                }
                s6 |= (1u << bq);
                oi[r] = bidx; ov[r] = best;
            }
            i0 = oi[0]; i1 = oi[1]; i2 = oi[2];
            const float e1 = __expf((float)((ov[1] - ov[0]) * 0.2));
            const float e2 = __expf((float)((ov[2] - ov[0]) * 0.2));
            const float inv = 1.0f / (1.0f + e1 + e2);
            a0 = inv; a1 = e1 * inv; a2 = e2 * inv;
        }

        // ---- write activations (32 floats, 3 nonzero) ----
        float4* __restrict__ o4 =
            reinterpret_cast<float4*>(act_out) + (size_t)row * (NB / 4);
#pragma unroll
        for (int j = 0; j < NB / 4; ++j) {
            float4 o;
            const int nb = 4 * j;
            o.x = (nb+0 == i0) ? a0 : (nb+0 == i1) ? a1 : (nb+0 == i2) ? a2 : 0.0f;
            o.y = (nb+1 == i0) ? a0 : (nb+1 == i1) ? a1 : (nb+1 == i2) ? a2 : 0.0f;
            o.z = (nb+2 == i0) ? a0 : (nb+2 == i1) ? a1 : (nb+2 == i2) ? a2 : 0.0f;
            o.w = (nb+3 == i0) ? a0 : (nb+3 == i1) ? a1 : (nb+3 == i2) ? a2 : 0.0f;
            o4[j] = o;
        }

        assign_out[row] = (float)i0;
        atomicAdd(&hist[i0], 1);
    }

    __syncthreads();
    if (threadIdx.x < NB) {
        // rotate bin order by block to spread same-address atomic contention
        const int b = (threadIdx.x + blockIdx.x) & (NB - 1);
        const int c = hist[b];
        if (c > 0) atomicAdd(&util_out[b], (float)c);
    }
}

extern "C" void kernel_launch(void* const* d_in, const int* in_sizes, int n_in,
                              void* d_out, int out_size, void* d_ws, size_t ws_size,
                              hipStream_t stream) {
    const float* z      = (const float*)d_in[0];
    const float* protos = (const float*)d_in[1];
    const float* util   = (const float*)d_in[2];
    const int nrows = in_sizes[0] / D;

    float* act_out    = (float*)d_out;
    float* assign_out = act_out + (size_t)nrows * NB;
    float* util_out   = assign_out + nrows;

    util_init_kernel<<<1, 64, 0, stream>>>(util, util_out);
    const int blocks = (nrows + 255) / 256;
    geocore_kernel<<<blocks, 256, 0, stream>>>(z, protos, act_out, assign_out,
                                               util_out, nrows);
}

// Round 3
// 434.941 us; speedup vs baseline: 1.6345x; 1.2867x over previous
//
#include <hip/hip_runtime.h>

typedef float v2f __attribute__((ext_vector_type(2)));

constexpr int NB = 32;   // basins
constexpr int D  = 64;   // core dim
constexpr int D4 = 16;   // D/4

// Prep: transpose prototypes into d_ws as protosT[j][n] (j=dim, n=basin),
// and copy utilization into the output tail.
__global__ void prep_kernel(const float* __restrict__ protos,
                            const float* __restrict__ util_in,
                            float* __restrict__ protosT,
                            float* __restrict__ util_out) {
    const int t = threadIdx.x;
    for (int i = t; i < NB * D; i += 256) {
        const int j = i >> 5;        // dim index
        const int n = i & (NB - 1);  // basin index
        protosT[i] = protos[n * D + j];
    }
    if (t < NB) util_out[t] = util_in[t];
}

__global__ __launch_bounds__(256, 6) void geocore_kernel(
    const float* __restrict__ z,
    const float* __restrict__ protosT,   // [D][NB] transposed, in d_ws
    const float* __restrict__ protos,    // [NB][D] original (slow path)
    float* __restrict__ act_out,
    float* __restrict__ assign_out,
    float* __restrict__ util_out,
    int nrows)
{
    __shared__ int hist[NB];
    if (threadIdx.x < NB) hist[threadIdx.x] = 0;
    __syncthreads();

    const int row = blockIdx.x * blockDim.x + threadIdx.x;

    if (row < nrows) {
        const float4* __restrict__ z4 =
            reinterpret_cast<const float4*>(z) + (size_t)row * D4;
        const v2f* __restrict__ pT = reinterpret_cast<const v2f*>(protosT);

        // ---- packed f32 sims: acc[p] holds {sims[2p], sims[2p+1]} ----
        v2f acc[NB / 2];
#pragma unroll
        for (int p = 0; p < NB / 2; ++p) acc[p] = (v2f){0.0f, 0.0f};

#pragma unroll
        for (int g = 0; g < 4; ++g) {
            float zg[16];
#pragma unroll
            for (int q = 0; q < 4; ++q) {
                float4 t = z4[4 * g + q];
                zg[4 * q + 0] = t.x; zg[4 * q + 1] = t.y;
                zg[4 * q + 2] = t.z; zg[4 * q + 3] = t.w;
            }
#pragma unroll
            for (int jj = 0; jj < 16; ++jj) {
                const int j = g * 16 + jj;
                const v2f zz = (v2f){zg[jj], zg[jj]};
                const v2f* __restrict__ prow = pT + j * (NB / 2);
#pragma unroll
                for (int p = 0; p < NB / 2; ++p)
                    acc[p] = zz * prow[p] + acc[p];
            }
        }

        float sims[NB];
#pragma unroll
        for (int p = 0; p < NB / 2; ++p) {
            sims[2 * p + 0] = acc[p].x;
            sims[2 * p + 1] = acc[p].y;
        }

        // ---- f32 top-4 (ties -> lowest index via strict >) ----
        float tv[4]; int ti[4];
        unsigned sel = 0u;
#pragma unroll
        for (int r = 0; r < 4; ++r) {
            float best = -1.0e30f; int bi = 0;
#pragma unroll
            for (int n = 0; n < NB; ++n) {
                bool take = (((sel >> n) & 1u) == 0u) && (sims[n] > best);
                best = take ? sims[n] : best;
                bi   = take ? n : bi;
            }
            sel |= (1u << bi);
            tv[r] = best; ti[r] = bi;
        }

        int i0 = ti[0], i1 = ti[1], i2 = ti[2];
        float a0, a1, a2;

        // f32 dot error vs f64 golden < ~4e-6; if every adjacent gap among
        // top-4 exceeds EPS, the f32 ordering provably matches f64.
        const float EPS = 1.0e-5f;
        const bool ambiguous = (tv[0] - tv[1] < EPS) ||
                               (tv[1] - tv[2] < EPS) ||
                               (tv[2] - tv[3] < EPS);

        if (!ambiguous) {
            const float e1 = __expf((tv[1] - tv[0]) * 0.2f);
            const float e2 = __expf((tv[2] - tv[0]) * 0.2f);
            const float inv = 1.0f / (1.0f + e1 + e2);
            a0 = inv; a1 = e1 * inv; a2 = e2 * inv;
        } else {
            // ---- rare slow path: extend to top-6, refine in f64 ----
            int cand[6];
            cand[0] = ti[0]; cand[1] = ti[1]; cand[2] = ti[2]; cand[3] = ti[3];
#pragma unroll
            for (int r = 4; r < 6; ++r) {
                float best = -1.0e30f; int bi = 0;
#pragma unroll
                for (int n = 0; n < NB; ++n) {
                    bool take = (((sel >> n) & 1u) == 0u) && (sims[n] > best);
                    best = take ? sims[n] : best;
                    bi   = take ? n : bi;
                }
                sel |= (1u << bi);
                cand[r] = bi;
            }

            double cv[6];
#pragma unroll
            for (int c = 0; c < 6; ++c) cv[c] = 0.0;
            for (int g = 0; g < 4; ++g) {
                float zc[16];
#pragma unroll
                for (int q = 0; q < 4; ++q) {
                    float4 t = z4[4 * g + q];
                    zc[4 * q + 0] = t.x; zc[4 * q + 1] = t.y;
                    zc[4 * q + 2] = t.z; zc[4 * q + 3] = t.w;
                }
#pragma unroll
                for (int c = 0; c < 6; ++c) {
                    const float* __restrict__ p = protos + cand[c] * D + g * 16;
                    double a = cv[c];
#pragma unroll
                    for (int j = 0; j < 16; ++j)
                        a = fma((double)zc[j], (double)p[j], a);
                    cv[c] = a;
                }
            }

            int oi[3]; double ov[3];
            unsigned s6 = 0u;
#pragma unroll
            for (int r = 0; r < 3; ++r) {
                double best = -1.0e300; int bq = 0, bidx = 1000;
#pragma unroll
                for (int q = 0; q < 6; ++q) {
                    bool free_ = (((s6 >> q) & 1u) == 0u);
                    bool take = free_ && ((cv[q] > best) ||
                                          (cv[q] == best && cand[q] < bidx));
                    best = take ? cv[q] : best;
                    bq   = take ? q : bq;
                    bidx = take ? cand[q] : bidx;
                }
                s6 |= (1u << bq);
                oi[r] = bidx; ov[r] = best;
            }
            i0 = oi[0]; i1 = oi[1]; i2 = oi[2];
            const float e1 = __expf((float)((ov[1] - ov[0]) * 0.2));
            const float e2 = __expf((float)((ov[2] - ov[0]) * 0.2));
            const float inv = 1.0f / (1.0f + e1 + e2);
            a0 = inv; a1 = e1 * inv; a2 = e2 * inv;
        }

        // ---- write activations (32 floats, 3 nonzero) ----
        float4* __restrict__ o4 =
            reinterpret_cast<float4*>(act_out) + (size_t)row * (NB / 4);
#pragma unroll
        for (int j = 0; j < NB / 4; ++j) {
            float4 o;
            const int nb = 4 * j;
            o.x = (nb+0 == i0) ? a0 : (nb+0 == i1) ? a1 : (nb+0 == i2) ? a2 : 0.0f;
            o.y = (nb+1 == i0) ? a0 : (nb+1 == i1) ? a1 : (nb+1 == i2) ? a2 : 0.0f;
            o.z = (nb+2 == i0) ? a0 : (nb+2 == i1) ? a1 : (nb+2 == i2) ? a2 : 0.0f;
            o.w = (nb+3 == i0) ? a0 : (nb+3 == i1) ? a1 : (nb+3 == i2) ? a2 : 0.0f;
            o4[j] = o;
        }

        assign_out[row] = (float)i0;
        atomicAdd(&hist[i0], 1);
    }

    __syncthreads();
    if (threadIdx.x < NB) {
        const int b = (threadIdx.x + blockIdx.x) & (NB - 1);
        const int c = hist[b];
        if (c > 0) atomicAdd(&util_out[b], (float)c);
    }
}

extern "C" void kernel_launch(void* const* d_in, const int* in_sizes, int n_in,
                              void* d_out, int out_size, void* d_ws, size_t ws_size,
                              hipStream_t stream) {
    const float* z      = (const float*)d_in[0];
    const float* protos = (const float*)d_in[1];
    const float* util   = (const float*)d_in[2];
    const int nrows = in_sizes[0] / D;

    float* act_out    = (float*)d_out;
    float* assign_out = act_out + (size_t)nrows * NB;
    float* util_out   = assign_out + nrows;
    float* protosT    = (float*)d_ws;   // 8 KB

    prep_kernel<<<1, 256, 0, stream>>>(protos, util, protosT, util_out);
    const int blocks = (nrows + 255) / 256;
    geocore_kernel<<<blocks, 256, 0, stream>>>(z, protosT, protos, act_out,
                                               assign_out, util_out, nrows);
}